// Round 3
// baseline (55.158 us; speedup 1.0000x reference)
//
#include <hip/hip_runtime.h>

#define HH 512
#define WW 512
#define NB 8
constexpr int   NPIX = HH * WW;              // 262144 pixels per batch
constexpr int   FH   = (HH - 1) * (WW - 1);  // 261121 lower faces per batch
constexpr int   NF   = 2 * FH;               // 522242 faces per batch
constexpr float EPS       = 0.04f;
constexpr float DEPTH_MIN = 0.1f;
constexpr float EDGE_MAX  = 0.1f;

__device__ __forceinline__ void load8(float* d, const float* p) {
    float4 u0 = *(const float4*)p;          // p is 32B aligned (col multiple of 8)
    float4 u1 = *(const float4*)(p + 4);
    d[0]=u0.x; d[1]=u0.y; d[2]=u0.z; d[3]=u0.w;
    d[4]=u1.x; d[5]=u1.y; d[6]=u1.z; d[7]=u1.w;
}

// store 8 xyz triples (24 floats, 16B-aligned base) as 6 float4
__device__ __forceinline__ void store24(float* dst, const float* x,
                                        const float* y, const float* z) {
    float4* d = (float4*)dst;
    d[0] = make_float4(x[0], y[0], z[0], x[1]);
    d[1] = make_float4(y[1], z[1], x[2], y[2]);
    d[2] = make_float4(z[2], x[3], y[3], z[3]);
    d[3] = make_float4(x[4], y[4], z[4], x[5]);
    d[4] = make_float4(y[5], z[5], x[6], y[6]);
    d[5] = make_float4(z[6], x[7], y[7], z[7]);
}

__device__ __forceinline__ float elen(float ax, float ay, float az,
                                      float bx, float by, float bz) {
    float dx = ax - bx, dy = ay - by, dz = az - bz;
    return sqrtf(dx * dx + dy * dy + dz * dz);
}

// One wave = (batch b, face-row y). Lane owns 8 columns. Fully fused:
// loads z rows y,y+1 + a row y; computes v both rows in registers; stores
// v/a row y (wave y==510 also row 511); faces from registers + 1-lane shuffle.
__global__ void __launch_bounds__(256)
fused_kernel(const float* __restrict__ attr_d,
             const float* __restrict__ c2w_int,
             const float* __restrict__ c2w_ext,
             float* __restrict__ out_v,
             float* __restrict__ out_a,
             float* __restrict__ out_e,
             float* __restrict__ out_m) {
    const int wid  = threadIdx.x >> 6;
    const int lane = threadIdx.x & 63;
    const int y    = blockIdx.x * 4 + wid;
    if (y >= HH - 1) return;                 // 511 face rows
    const int b  = blockIdx.y;
    const int c0 = lane << 3;                // first of 8 owned columns

    const float* base = attr_d + (size_t)b * 4 * NPIX;   // planar (C,H,W)
    const float* K = c2w_int + b * 9;                    // uniform -> s_loads
    const float* E = c2w_ext + b * 12;
    const float K0=K[0],K1=K[1],K2=K[2],K3=K[3],K4=K[4],K5=K[5],K6=K[6],K7=K[7],K8=K[8];
    const float E0=E[0],E1=E[1],E2=E[2],E3=E[3],E4=E[4],E5=E[5],
                E6=E[6],E7=E[7],E8=E[8],E9=E[9],E10=E[10],E11=E[11];

    float z0[8], z1[8];
    load8(z0, base + 3*NPIX + (size_t)y * WW + c0);
    load8(z1, base + 3*NPIX + (size_t)(y+1) * WW + c0);

    // attributes row y (+ col-511 extension; y<=510 so the rule applies)
    float a0[3][8];
#pragma unroll
    for (int c = 0; c < 3; ++c) load8(a0[c], base + c*NPIX + (size_t)y * WW + c0);
    if (lane == 63) {
#pragma unroll
        for (int c = 0; c < 3; ++c) a0[c][7] += (a0[c][7] - a0[c][6]) * EPS;
    }

    // unproject both rows
    float v0x[8],v0y[8],v0z[8], v1x[8],v1y[8],v1z[8];
    const float yc0 = (float)y + 0.5f;
    const float yc1 = (y + 1 == HH - 1) ? ((float)HH - 0.5f + EPS)
                                        : ((float)(y + 1) + 0.5f);
#pragma unroll
    for (int j = 0; j < 8; ++j) {
        float xc = (float)(c0 + j) + 0.5f;
        if (c0 + j == WW - 1) xc = (float)WW - 0.5f + EPS;
        {
            float p0 = xc*z0[j], p1 = yc0*z0[j], p2 = z0[j];
            float vi0 = K0*p0 + K1*p1 + K2*p2;
            float vi1 = K3*p0 + K4*p1 + K5*p2;
            float vi2 = K6*p0 + K7*p1 + K8*p2;
            v0x[j] = E0*vi0 + E1*vi1 + E2 *vi2 + E3;
            v0y[j] = E4*vi0 + E5*vi1 + E6 *vi2 + E7;
            v0z[j] = E8*vi0 + E9*vi1 + E10*vi2 + E11;
        }
        {
            float p0 = xc*z1[j], p1 = yc1*z1[j], p2 = z1[j];
            float vi0 = K0*p0 + K1*p1 + K2*p2;
            float vi1 = K3*p0 + K4*p1 + K5*p2;
            float vi2 = K6*p0 + K7*p1 + K8*p2;
            v1x[j] = E0*vi0 + E1*vi1 + E2 *vi2 + E3;
            v1y[j] = E4*vi0 + E5*vi1 + E6 *vi2 + E7;
            v1z[j] = E8*vi0 + E9*vi1 + E10*vi2 + E11;
        }
    }

    // store v,a for row y
    size_t rowbase = ((size_t)b * NPIX + (size_t)y * WW + c0) * 3;
    store24(out_v + rowbase, v0x, v0y, v0z);
    store24(out_a + rowbase, a0[0], a0[1], a0[2]);

    // wave y==510 also owns row 511 (v + a with last-row/corner extension)
    if (y == HH - 2) {
        float a1[3][8];
#pragma unroll
        for (int c = 0; c < 3; ++c) {
            load8(a1[c], base + c*NPIX + (size_t)(HH-1) * WW + c0);
#pragma unroll
            for (int j = 0; j < 8; ++j) {   // last-row rule, cols 0..510
                if (c0 + j < WW - 1) a1[c][j] += (a1[c][j] - a0[c][j]) * EPS;
            }
        }
        if (lane == 63) {                    // corner uses diag a[510][510]
#pragma unroll
            for (int c = 0; c < 3; ++c) a1[c][7] += (a1[c][7] - a0[c][6]) * EPS;
        }
        size_t rb1 = ((size_t)b * NPIX + (size_t)(HH-1) * WW + c0) * 3;
        store24(out_v + rb1, v1x, v1y, v1z);
        store24(out_a + rb1, a1[0], a1[1], a1[2]);
    }

    // neighbor column (c0+8) from lane+1; lane 63's values are never used
    float n0x = __shfl_down(v0x[0], 1), n0y = __shfl_down(v0y[0], 1), n0z = __shfl_down(v0z[0], 1);
    float n1x = __shfl_down(v1x[0], 1), n1y = __shfl_down(v1y[0], 1), n1z = __shfl_down(v1z[0], 1);
    float zn0 = __shfl_down(z0[0], 1),  zn1 = __shfl_down(z1[0], 1);

    // 9 shared vertical edges (cols c0..c0+8)
    float vert[9];
#pragma unroll
    for (int j = 0; j < 8; ++j)
        vert[j] = elen(v0x[j],v0y[j],v0z[j], v1x[j],v1y[j],v1z[j]);
    vert[8] = elen(n0x,n0y,n0z, n1x,n1y,n1z);

    size_t elo = ((size_t)b * NF + (size_t)y * (WW-1)) * 3;
    size_t eup = elo + (size_t)FH * 3;
    size_t mlo = (size_t)b * NF + (size_t)y * (WW-1);
    size_t mup = mlo + FH;

#pragma unroll
    for (int j = 0; j < 8; ++j) {
        float bx = (j < 7) ? v0x[j+1] : n0x;   // row y,   col x+1
        float by = (j < 7) ? v0y[j+1] : n0y;
        float bz = (j < 7) ? v0z[j+1] : n0z;
        float cx = (j < 7) ? v1x[j+1] : n1x;   // row y+1, col x+1
        float cy = (j < 7) ? v1y[j+1] : n1y;
        float cz = (j < 7) ? v1z[j+1] : n1z;
        float zt1 = (j < 7) ? z0[j+1] : zn0;
        float zb1 = (j < 7) ? z1[j+1] : zn1;

        float top  = elen(v0x[j],v0y[j],v0z[j], bx,by,bz);
        float bot  = elen(v1x[j],v1y[j],v1z[j], cx,cy,cz);
        float diag = elen(v0x[j],v0y[j],v0z[j], cx,cy,cz);

        bool ml = (z0[j] > DEPTH_MIN) & (z1[j] > DEPTH_MIN) & (zb1 > DEPTH_MIN) &
                  (vert[j] < EDGE_MAX) & (bot < EDGE_MAX) & (diag < EDGE_MAX);
        bool mu = (z0[j] > DEPTH_MIN) & (zb1 > DEPTH_MIN) & (zt1 > DEPTH_MIN) &
                  (diag < EDGE_MAX) & (vert[j+1] < EDGE_MAX) & (top < EDGE_MAX);

        if (j < 7 || lane != 63) {             // quad x=511 doesn't exist
            int x = c0 + j;
            out_e[elo + (size_t)x*3 + 0] = vert[j];
            out_e[elo + (size_t)x*3 + 1] = bot;
            out_e[elo + (size_t)x*3 + 2] = diag;
            out_e[eup + (size_t)x*3 + 0] = diag;
            out_e[eup + (size_t)x*3 + 1] = vert[j+1];
            out_e[eup + (size_t)x*3 + 2] = top;
            out_m[mlo + x] = ml ? 1.0f : 0.0f;
            out_m[mup + x] = mu ? 1.0f : 0.0f;
        }
    }
}

extern "C" void kernel_launch(void* const* d_in, const int* in_sizes, int n_in,
                              void* d_out, int out_size, void* d_ws, size_t ws_size,
                              hipStream_t stream) {
    const float* attr_d  = (const float*)d_in[0];
    const float* c2w_int = (const float*)d_in[1];
    const float* c2w_ext = (const float*)d_in[2];

    float* out   = (float*)d_out;
    float* out_v = out;                                  // B*N*3
    float* out_a = out + (size_t)NB * NPIX * 3;          // B*N*3
    float* out_e = out + (size_t)2 * NB * NPIX * 3;      // B*F*3
    float* out_m = out_e + (size_t)NB * NF * 3;          // B*F

    dim3 grid(128, NB);                                  // 4 face-rows per block
    fused_kernel<<<grid, 256, 0, stream>>>(attr_d, c2w_int, c2w_ext,
                                           out_v, out_a, out_e, out_m);
}

// Round 4
// 28.142 us; speedup vs baseline: 1.9600x; 1.9600x over previous
//
#include <hip/hip_runtime.h>

#define HH 512
#define WW 512
#define NB 8
constexpr int   NPIX = HH * WW;              // 262144 pixels per batch
constexpr int   FH   = (HH - 1) * (WW - 1);  // 261121 lower faces per batch
constexpr int   NF   = 2 * FH;               // 522242 faces per batch
constexpr float EPS       = 0.04f;
constexpr float DEPTH_MIN = 0.1f;
constexpr float EDGE_MAX  = 0.1f;

__device__ __forceinline__ float elen(float ax, float ay, float az,
                                      float bx, float by, float bz) {
    float dx = ax - bx, dy = ay - by, dz = az - bz;
    return sqrtf(dx * dx + dy * dy + dz * dz);
}

// neighbor-column fetch: value of the (col+1) owner.
// col = lane + 64*j; col+1 owner is lane+1 (same j) except lane 63 -> lane 0, j+1.
// Source lane s=(lane+1)&63 contributes nxt if s==0 else cur.
__device__ __forceinline__ float nbr(float cur, float nxt, int lane) {
    float t = (lane == 0) ? nxt : cur;
    return __shfl(t, (lane + 1) & 63);
}

// per-wave LDS -> global copy of n floats; d is 4B-aligned, head fixup to 16B.
// Single-wave workgroup: no barrier needed (wave-ordered DS + alias ordering).
__device__ __forceinline__ void wcopy(const float* __restrict__ s,
                                      float* __restrict__ d, int n, int lane) {
    int head = (int)(((16u - (unsigned)((uintptr_t)d & 15u)) & 15u) >> 2);
    if (head > n) head = n;
    if (lane < head) d[lane] = s[lane];
    int n4 = (n - head) >> 2;
    const float* s2 = s + head;
    float* d2 = d + head;            // 16B aligned
    for (int i = lane; i < n4; i += 64) {
        float4 t = make_float4(s2[4*i], s2[4*i+1], s2[4*i+2], s2[4*i+3]);
        *(float4*)(d2 + 4*i) = t;    // 1024B contiguous per instruction
    }
    int done = n4 << 2;
    int rem  = n - head - done;
    if (lane < rem) d2[done + lane] = s2[done + lane];
}

// One wave (= one 64-thread workgroup) handles (batch b, face-row y).
// Lane owns interleaved columns lane + 64*j, j=0..7.
__global__ void __launch_bounds__(64)
fused_kernel(const float* __restrict__ attr_d,
             const float* __restrict__ c2w_int,
             const float* __restrict__ c2w_ext,
             float* __restrict__ out_v,
             float* __restrict__ out_a,
             float* __restrict__ out_e,
             float* __restrict__ out_m) {
    __shared__ float lds[1536];
    const int lane = threadIdx.x;
    const int task = blockIdx.x;             // b*511 + y
    const int b    = task / 511;
    const int y    = task - b * 511;

    const float* base  = attr_d + (size_t)b * 4 * NPIX;  // planar (C,H,W)
    const float* zrow0 = base + 3 * NPIX + (size_t)y * WW;
    const float* zrow1 = zrow0 + WW;

    float z0[8], z1[8], a0[3][8];
#pragma unroll
    for (int j = 0; j < 8; ++j) {            // 4B-stride coalesced loads
        z0[j] = zrow0[lane + 64*j];
        z1[j] = zrow1[lane + 64*j];
    }
#pragma unroll
    for (int c = 0; c < 3; ++c) {
        const float* ar = base + c * NPIX + (size_t)y * WW;
#pragma unroll
        for (int j = 0; j < 8; ++j) a0[c][j] = ar[lane + 64*j];
    }

    // col-511 attribute extension (applies to rows 0..510; here y<=510)
#pragma unroll
    for (int c = 0; c < 3; ++c) {
        float left = __shfl_up(a0[c][7], 1);         // lane63 <- col510 value
        if (lane == 63) a0[c][7] += (a0[c][7] - left) * EPS;
    }

    const float* K = c2w_int + b * 9;
    const float* E = c2w_ext + b * 12;
    const float K0=K[0],K1=K[1],K2=K[2],K3=K[3],K4=K[4],K5=K[5],K6=K[6],K7=K[7],K8=K[8];
    const float E0=E[0],E1=E[1],E2=E[2],E3=E[3],E4=E[4],E5=E[5],
                E6=E[6],E7=E[7],E8=E[8],E9=E[9],E10=E[10],E11=E[11];

    const float yc0 = (float)y + 0.5f;
    const float yc1 = (y + 1 == HH - 1) ? ((float)HH - 0.5f + EPS)
                                        : ((float)(y + 1) + 0.5f);

    float v0x[8],v0y[8],v0z[8], v1x[8],v1y[8],v1z[8];
#pragma unroll
    for (int j = 0; j < 8; ++j) {
        int col = lane + 64*j;
        float xc = (col == WW - 1) ? ((float)WW - 0.5f + EPS) : ((float)col + 0.5f);
        {
            float p0 = xc*z0[j], p1 = yc0*z0[j], p2 = z0[j];
            float vi0 = K0*p0 + K1*p1 + K2*p2;
            float vi1 = K3*p0 + K4*p1 + K5*p2;
            float vi2 = K6*p0 + K7*p1 + K8*p2;
            v0x[j] = E0*vi0 + E1*vi1 + E2 *vi2 + E3;
            v0y[j] = E4*vi0 + E5*vi1 + E6 *vi2 + E7;
            v0z[j] = E8*vi0 + E9*vi1 + E10*vi2 + E11;
        }
        {
            float p0 = xc*z1[j], p1 = yc1*z1[j], p2 = z1[j];
            float vi0 = K0*p0 + K1*p1 + K2*p2;
            float vi1 = K3*p0 + K4*p1 + K5*p2;
            float vi2 = K6*p0 + K7*p1 + K8*p2;
            v1x[j] = E0*vi0 + E1*vi1 + E2 *vi2 + E3;
            v1y[j] = E4*vi0 + E5*vi1 + E6 *vi2 + E7;
            v1z[j] = E8*vi0 + E9*vi1 + E10*vi2 + E11;
        }
    }

    // ---- v row y, a row y: LDS transpose -> fully coalesced float4 stores
    size_t rb = ((size_t)b * NPIX + (size_t)y * WW) * 3;   // 16B aligned
#pragma unroll
    for (int j = 0; j < 8; ++j) {
        int c3 = (lane + 64*j) * 3;                        // bank stride 3: 2-way, free
        lds[c3] = v0x[j]; lds[c3+1] = v0y[j]; lds[c3+2] = v0z[j];
    }
    wcopy(lds, out_v + rb, 1536, lane);
#pragma unroll
    for (int j = 0; j < 8; ++j) {
        int c3 = (lane + 64*j) * 3;
        lds[c3] = a0[0][j]; lds[c3+1] = a0[1][j]; lds[c3+2] = a0[2][j];
    }
    wcopy(lds, out_a + rb, 1536, lane);

    // ---- edges + masks
    float vert[8];
#pragma unroll
    for (int j = 0; j < 8; ++j)
        vert[j] = elen(v0x[j],v0y[j],v0z[j], v1x[j],v1y[j],v1z[j]);

    float bot[8], diag[8], top[8], vertn[8];
    size_t mlo = (size_t)b * NF + (size_t)y * (WW-1);
    size_t mup = mlo + FH;
#pragma unroll
    for (int j = 0; j < 8; ++j) {
        const int jn = (j < 7) ? j + 1 : j;   // j==7 nxt only feeds unused lane63
        float n0x = nbr(v0x[j], v0x[jn], lane);
        float n0y = nbr(v0y[j], v0y[jn], lane);
        float n0z = nbr(v0z[j], v0z[jn], lane);
        float n1x = nbr(v1x[j], v1x[jn], lane);
        float n1y = nbr(v1y[j], v1y[jn], lane);
        float n1z = nbr(v1z[j], v1z[jn], lane);
        float zt1 = nbr(z0[j],  z0[jn],  lane);
        float zb1 = nbr(z1[j],  z1[jn],  lane);
        vertn[j]  = nbr(vert[j], vert[jn], lane);

        top[j]  = elen(v0x[j],v0y[j],v0z[j], n0x,n0y,n0z);
        bot[j]  = elen(v1x[j],v1y[j],v1z[j], n1x,n1y,n1z);
        diag[j] = elen(v0x[j],v0y[j],v0z[j], n1x,n1y,n1z);

        bool ml = (z0[j] > DEPTH_MIN) & (z1[j] > DEPTH_MIN) & (zb1 > DEPTH_MIN) &
                  (vert[j] < EDGE_MAX) & (bot[j] < EDGE_MAX) & (diag[j] < EDGE_MAX);
        bool mu = (z0[j] > DEPTH_MIN) & (zb1 > DEPTH_MIN) & (zt1 > DEPTH_MIN) &
                  (diag[j] < EDGE_MAX) & (vertn[j] < EDGE_MAX) & (top[j] < EDGE_MAX);

        int col = lane + 64*j;
        if (col < WW - 1) {                   // 4B-stride coalesced mask stores
            out_m[mlo + col] = ml ? 1.0f : 0.0f;
            out_m[mup + col] = mu ? 1.0f : 0.0f;
        }
    }

    size_t elo = mlo * 3;
#pragma unroll
    for (int j = 0; j < 8; ++j) {
        int col = lane + 64*j;
        if (col < WW - 1) {
            int c3 = col * 3;
            lds[c3] = vert[j]; lds[c3+1] = bot[j]; lds[c3+2] = diag[j];
        }
    }
    wcopy(lds, out_e + elo, 1533, lane);
#pragma unroll
    for (int j = 0; j < 8; ++j) {
        int col = lane + 64*j;
        if (col < WW - 1) {
            int c3 = col * 3;
            lds[c3] = diag[j]; lds[c3+1] = vertn[j]; lds[c3+2] = top[j];
        }
    }
    wcopy(lds, out_e + elo + (size_t)FH * 3, 1533, lane);

    // ---- wave y==510 also owns pixel row 511 (v + extended a)
    if (y == HH - 2) {
        float a1[3][8];
#pragma unroll
        for (int c = 0; c < 3; ++c) {
            const float* ar = base + c * NPIX + (size_t)(HH-1) * WW;
#pragma unroll
            for (int j = 0; j < 8; ++j) a1[c][j] = ar[lane + 64*j];
            float dl = __shfl_up(a0[c][7], 1);       // col510 row510 (original)
#pragma unroll
            for (int j = 0; j < 8; ++j) {            // last-row rule, cols 0..510
                int col = lane + 64*j;
                if (col < WW - 1) a1[c][j] += (a1[c][j] - a0[c][j]) * EPS;
            }
            if (lane == 63) a1[c][7] += (a1[c][7] - dl) * EPS;   // corner: diag
        }
        size_t rb1 = ((size_t)b * NPIX + (size_t)(HH-1) * WW) * 3;
#pragma unroll
        for (int j = 0; j < 8; ++j) {
            int c3 = (lane + 64*j) * 3;
            lds[c3] = v1x[j]; lds[c3+1] = v1y[j]; lds[c3+2] = v1z[j];
        }
        wcopy(lds, out_v + rb1, 1536, lane);
#pragma unroll
        for (int j = 0; j < 8; ++j) {
            int c3 = (lane + 64*j) * 3;
            lds[c3] = a1[0][j]; lds[c3+1] = a1[1][j]; lds[c3+2] = a1[2][j];
        }
        wcopy(lds, out_a + rb1, 1536, lane);
    }
}

extern "C" void kernel_launch(void* const* d_in, const int* in_sizes, int n_in,
                              void* d_out, int out_size, void* d_ws, size_t ws_size,
                              hipStream_t stream) {
    const float* attr_d  = (const float*)d_in[0];
    const float* c2w_int = (const float*)d_in[1];
    const float* c2w_ext = (const float*)d_in[2];

    float* out   = (float*)d_out;
    float* out_v = out;                                  // B*N*3
    float* out_a = out + (size_t)NB * NPIX * 3;          // B*N*3
    float* out_e = out + (size_t)2 * NB * NPIX * 3;      // B*F*3
    float* out_m = out_e + (size_t)NB * NF * 3;          // B*F

    int tasks = NB * (HH - 1);                           // 4088 wave-tasks
    fused_kernel<<<tasks, 64, 0, stream>>>(attr_d, c2w_int, c2w_ext,
                                           out_v, out_a, out_e, out_m);
}